// Round 3
// baseline (398.412 us; speedup 1.0000x reference)
//
#include <hip/hip_runtime.h>

#define D 128
#define LSTR 132       // padded LDS row stride (floats)
#define HB 256         // degree-histogram block count
#define SCAN_NPB 4096  // nodes per scan block (256 thr x 16)
#define NBUF 3         // stage buffers per wave (triple buffer)

typedef __attribute__((ext_vector_type(8))) short short8;
typedef __attribute__((ext_vector_type(4))) float f32x4;

static __device__ __forceinline__ unsigned short f2bf(float f) {
    unsigned u = __float_as_uint(f);
    return (unsigned short)((u + 0x7fffu + ((u >> 16) & 1u)) >> 16);  // RNE
}

// Fire-and-forget global->LDS DMA: per-lane global addr, LDS dest =
// wave-uniform base + lane*16. Tracked by vmcnt, zero VGPR per in-flight byte.
static __device__ __forceinline__ void gload_lds16(const unsigned short* g,
                                                   unsigned* l) {
    __builtin_amdgcn_global_load_lds(
        (const __attribute__((address_space(1))) void*)g,
        (__attribute__((address_space(3))) void*)l, 16, 0, 0);
}

// ---------------------------------------------------------------------------
// GraphSAGE (mean) x2 + head. bf16 features (fp32 accumulate).
// Row-sorted CSR via global-atomic counting sort:
//   P1 prep+hist: cast x->bf16 (float4/thread), transpose weights; deg hist
//   P2 scan1: per-block (4096 nodes) degree sums -> bsum[13]
//   P3 scan2: per-block prefix over bsum + in-block scan -> cursor/tile_base/
//             invL_g
//   P4 fill: pos = atomicAdd(&cursor[dst]) -> csr[pos] = src | dst<<16
// sage: LDS-staged gather via global_load_lds (reg-free pipeline, vmcnt-
//   counted, triple-buffered; csr prefetched 2 stages ahead) -> segmented
//   accumulate -> MFMA dual GEMM. HEAD folds the Linear(128,1).
// ---------------------------------------------------------------------------

// Blocks [0, HB): global-atomic degree histogram. Blocks [HB, ...): prep.
__global__ __launch_bounds__(256) void prep_hist_kernel(
    const float* __restrict__ x, const float* __restrict__ W1l,
    const float* __restrict__ W1r, const float* __restrict__ W2l,
    const float* __restrict__ W2r, uint2* __restrict__ xb4,
    unsigned short* __restrict__ Bt1, unsigned short* __restrict__ Bt2,
    int NX4, const int* __restrict__ dst, int E, int* __restrict__ deg) {
    const int t = threadIdx.x;
    if (blockIdx.x < HB) {
        const int per = (E + HB - 1) / HB;
        const int lo = blockIdx.x * per;
        const int hi = min(lo + per, E);
        for (int i = lo + t; i < hi; i += 256) atomicAdd(&deg[dst[i]], 1);
        return;
    }
    const int i = (blockIdx.x - HB) * 256 + t;
    if (i < NX4) {
        const float4 v = *(const float4*)(x + 4 * (size_t)i);
        uint2 o;
        o.x = (unsigned)f2bf(v.x) | ((unsigned)f2bf(v.y) << 16);
        o.y = (unsigned)f2bf(v.z) | ((unsigned)f2bf(v.w) << 16);
        xb4[i] = o;
    } else if (i < NX4 + 2 * 32768) {
        const int j = i - NX4;
        const int which = j >> 15;  // 0 -> layer1, 1 -> layer2
        const int jj = j & 32767;
        const int n = jj >> 8;
        const int k = jj & 255;
        const float* Wl = which ? W2l : W1l;
        const float* Wr = which ? W2r : W1r;
        const float w = (k < 128) ? Wl[k * 128 + n] : Wr[(k - 128) * 128 + n];
        (which ? Bt2 : Bt1)[jj] = f2bf(w);
    }
}

// Per-block degree sums (block = SCAN_NPB nodes).
__global__ __launch_bounds__(256) void scan1_kernel(const int* __restrict__ deg,
                                                    int N,
                                                    int* __restrict__ bsum) {
    const int t = threadIdx.x;
    const int lo = blockIdx.x * SCAN_NPB + t * 16;
    int s = 0;
    if (lo + 16 <= N) {
        const int4* p = (const int4*)(deg + lo);
#pragma unroll
        for (int i = 0; i < 4; ++i) {
            const int4 v = p[i];
            s += v.x + v.y + v.z + v.w;
        }
    } else {
        for (int i = lo; i < min(lo + 16, N); ++i) s += deg[i];
    }
#pragma unroll
    for (int off = 1; off < 64; off <<= 1) s += __shfl_xor(s, off, 64);
    __shared__ int ws[4];
    if ((t & 63) == 0) ws[t >> 6] = s;
    __syncthreads();
    if (t == 0) bsum[blockIdx.x] = ws[0] + ws[1] + ws[2] + ws[3];
}

// Grid-parallel scan: each block redundantly prefixes bsum, then in-block
// exclusive scan over its 4096 degrees -> cursor/tile_base/invL.
__global__ __launch_bounds__(256) void scan2_kernel(
    const int* __restrict__ deg, int N, int E, int nbins,
    const int* __restrict__ bsum, int* __restrict__ cursor,
    int* __restrict__ tile_base, float* __restrict__ invL_g) {
    __shared__ int ws[5];
    const int t = threadIdx.x;
    const int b = blockIdx.x;
    if (t == 0) {
        int base = 0;
        for (int i = 0; i < b; ++i) base += bsum[i];
        ws[4] = base;
    }
    const int lo = b * SCAN_NPB + t * 16;
    int d[16];
    int s = 0;
    if (lo + 16 <= N) {
        const int4* p = (const int4*)(deg + lo);
#pragma unroll
        for (int i = 0; i < 4; ++i) {
            const int4 v = p[i];
            d[4 * i + 0] = v.x;
            d[4 * i + 1] = v.y;
            d[4 * i + 2] = v.z;
            d[4 * i + 3] = v.w;
            s += v.x + v.y + v.z + v.w;
        }
    } else {
#pragma unroll
        for (int i = 0; i < 16; ++i) {
            d[i] = (lo + i < N) ? deg[lo + i] : 0;
            s += d[i];
        }
    }
    int sc = s;
#pragma unroll
    for (int off = 1; off < 64; off <<= 1) {
        const int u = __shfl_up(sc, off, 64);
        if ((t & 63) >= off) sc += u;
    }
    if ((t & 63) == 63) ws[t >> 6] = sc;
    __syncthreads();
    int run = ws[4] + sc - s;
    for (int w = 0; w < (t >> 6); ++w) run += ws[w];
#pragma unroll
    for (int i = 0; i < 16; ++i) {
        const int idx = lo + i;
        if (idx < N) {
            cursor[idx] = run;
            if ((idx & 31) == 0) tile_base[idx >> 5] = run;
            invL_g[idx] = 1.0f / fmaxf((float)d[i], 1.0f);
            run += d[i];
        }
    }
    if (b == 0 && t == 0) tile_base[nbins] = E;
}

// Scatter edges straight to final row-sorted position via atomic rank.
__global__ __launch_bounds__(256) void fill_kernel(
    const int* __restrict__ src, const int* __restrict__ dst, int E,
    int* __restrict__ cursor, unsigned* __restrict__ csr) {
    const int i = blockIdx.x * 256 + threadIdx.x;
    if (i < E) {
        const int d = dst[i];
        const int pos = atomicAdd(&cursor[d], 1);
        csr[pos] = (unsigned)src[i] | ((unsigned)d << 16);
    }
}

// Fused: LDS-staged gather (global_load_lds pipeline) -> segmented fp32
// accumulate into aggL -> MFMA dual GEMM (mean at A-frag build).
template <bool HEAD>
__global__ __launch_bounds__(256) void sage_kernel(
    const unsigned short* __restrict__ xb, const unsigned* __restrict__ csr,
    const int* __restrict__ tile_base, const float* __restrict__ invL_g,
    const unsigned short* __restrict__ Bt,  // [128 n][256 k] bf16
    const float* __restrict__ bl, const float* __restrict__ Wout,
    const float* __restrict__ bout, unsigned short* __restrict__ hb_out,
    float* __restrict__ out, int N) {
    __shared__ float aggL[32 * LSTR];
    __shared__ __align__(16) unsigned stageB[4][NBUF][8][64];  // 24 KiB
    __shared__ int rowid[4][NBUF][8];
    __shared__ float invL[32];
    __shared__ float redH[64];

    const int b = blockIdx.x;
    const int i0 = b * 32;
    const int t = threadIdx.x;
    const int wv = t >> 6;
    const int lane = t & 63;
    const int sub = lane >> 4;  // edge-within-quad 0..3
    const int cl = lane & 15;   // 16B-chunk index within the 256B row

    for (int i = t; i < 32 * LSTR; i += 256) aggL[i] = 0.f;
    if (t < 32) invL[t] = (i0 + t < N) ? invL_g[i0 + t] : 1.0f;
    __syncthreads();

    // ---- wave-pipelined staged gather over row-sorted csr ----
    const int rs0 = tile_base[b];
    const int re0 = tile_base[b + 1];
    const int nE = re0 - rs0;
    const int ws = rs0 + ((nE * wv) >> 2);
    const int we = rs0 + ((nE * (wv + 1)) >> 2);
    const int cnt = we - ws;
    const int nb = (cnt + 7) >> 3;
    const int lastc = re0 - 1;

    auto ldcs = [&](int s, unsigned& A, unsigned& B_) {
        const int e0 = ws + s * 8;
        A = csr[min(e0 + sub, lastc)];
        B_ = csr[min(e0 + 4 + sub, lastc)];
    };
    auto issue = [&](int s, unsigned A, unsigned B_) {
        unsigned* lp = &stageB[wv][s % NBUF][0][0];
        const unsigned short* gA = xb + (size_t)(A & 0xffffu) * D + cl * 8;
        const unsigned short* gB = xb + (size_t)(B_ & 0xffffu) * D + cl * 8;
        gload_lds16(gA, lp);        // edges e0..e0+3   (1 KiB)
        gload_lds16(gB, lp + 256);  // edges e0+4..e0+7 (1 KiB)
        if (cl == 0) {
            rowid[wv][s % NBUF][sub] = (int)(A >> 16);
            rowid[wv][s % NBUF][4 + sub] = (int)(B_ >> 16);
        }
    };

    float a0 = 0.f, a1 = 0.f;
    int cur = -1;
    if (nb > 0) {
        unsigned cA0, cB0, cA1, cB1, cA2 = 0, cB2 = 0;
        ldcs(0, cA0, cB0);
        if (nb > 1) ldcs(1, cA1, cB1);
        if (nb > 2) ldcs(2, cA2, cB2);
        issue(0, cA0, cB0);
        if (nb > 1) issue(1, cA1, cB1);
        for (int k = 0; k < nb; ++k) {
            if (k + 2 < nb) {
                // csr for stage k+3 first (keeps the auto-waitcnt on cA2's
                // value from draining the k+1 stage), then issue stage k+2.
                unsigned nA = 0, nB = 0;
                if (k + 3 < nb) ldcs(k + 3, nA, nB);
                issue(k + 2, cA2, cB2);
                cA2 = nA;
                cB2 = nB;
            } else if (k + 1 < nb) {
                asm volatile("s_waitcnt vmcnt(2)" ::: "memory");
            } else {
                asm volatile("s_waitcnt vmcnt(0)" ::: "memory");
            }
            __builtin_amdgcn_sched_barrier(0);
            // consume stage k from LDS
            const unsigned* sb = &stageB[wv][k % NBUF][0][0];
            const int* rd = &rowid[wv][k % NBUF][0];
            const int c = min(8, cnt - k * 8);
#pragma unroll
            for (int i = 0; i < 8; ++i) {
                if (i < c) {
                    const int r = rd[i] - i0;
                    const unsigned u = sb[i * 64 + lane];
                    if (r != cur) {
                        if (cur >= 0) {
                            atomicAdd(&aggL[cur * LSTR + 2 * lane], a0);
                            atomicAdd(&aggL[cur * LSTR + 2 * lane + 1], a1);
                        }
                        a0 = 0.f;
                        a1 = 0.f;
                        cur = r;
                    }
                    a0 += __uint_as_float(u << 16);
                    a1 += __uint_as_float(u & 0xffff0000u);
                }
            }
            __builtin_amdgcn_sched_barrier(0);
        }
        if (cur >= 0) {
            atomicAdd(&aggL[cur * LSTR + 2 * lane], a0);
            atomicAdd(&aggL[cur * LSTR + 2 * lane + 1], a1);
        }
    }
    __syncthreads();

    // ---- MFMA dual GEMM: [agg*inv | x](32x256) @ Bt^T(256x128) ----
    const int ln = lane & 15;
    const int quad = lane >> 4;
    const int mtile = wv & 1;       // rows mtile*16..+15
    const int nt0 = (wv >> 1) * 4;  // 4 n-tiles per wave
    const int mrow = mtile * 16 + ln;
    const int gmr = i0 + mrow;
    const float inv = invL[mrow];

    f32x4 acc4[4] = {f32x4{0.f, 0.f, 0.f, 0.f}, f32x4{0.f, 0.f, 0.f, 0.f},
                     f32x4{0.f, 0.f, 0.f, 0.f}, f32x4{0.f, 0.f, 0.f, 0.f}};

#pragma unroll
    for (int s = 0; s < 4; ++s) {
        const int kb = s * 32 + quad * 8;
        const float* ap = aggL + mrow * LSTR + kb;
        const float4 fa = *(const float4*)ap;
        const float4 fb = *(const float4*)(ap + 4);
        const short8 aA = {(short)f2bf(fa.x * inv), (short)f2bf(fa.y * inv),
                           (short)f2bf(fa.z * inv), (short)f2bf(fa.w * inv),
                           (short)f2bf(fb.x * inv), (short)f2bf(fb.y * inv),
                           (short)f2bf(fb.z * inv), (short)f2bf(fb.w * inv)};
        short8 aX = {0, 0, 0, 0, 0, 0, 0, 0};
        if (gmr < N) aX = *(const short8*)(xb + (size_t)gmr * D + kb);
#pragma unroll
        for (int nt = 0; nt < 4; ++nt) {
            const int n = (nt0 + nt) * 16 + ln;
            const short8 b1 = *(const short8*)(Bt + n * 256 + kb);
            const short8 b2 = *(const short8*)(Bt + n * 256 + 128 + kb);
            acc4[nt] = __builtin_amdgcn_mfma_f32_16x16x32_bf16(aA, b1, acc4[nt],
                                                               0, 0, 0);
            acc4[nt] = __builtin_amdgcn_mfma_f32_16x16x32_bf16(aX, b2, acc4[nt],
                                                               0, 0, 0);
        }
    }

    // ---- epilogue: C/D layout col=lane&15, row=quad*4+reg ----
    float biasv[4], woutv[4];
#pragma unroll
    for (int nt = 0; nt < 4; ++nt) {
        const int col = (nt0 + nt) * 16 + ln;
        biasv[nt] = bl[col];
        if (HEAD) woutv[nt] = Wout[col];
    }

    if (!HEAD) {
#pragma unroll
        for (int r = 0; r < 4; ++r) {
            const int gr = i0 + mtile * 16 + quad * 4 + r;
            if (gr < N) {
#pragma unroll
                for (int nt = 0; nt < 4; ++nt) {
                    const int col = (nt0 + nt) * 16 + ln;
                    const float v = fmaxf(acc4[nt][r] + biasv[nt], 0.f);
                    hb_out[(size_t)gr * D + col] = f2bf(v);
                }
            }
        }
    } else {
        const float b0 = bout[0];
#pragma unroll
        for (int r = 0; r < 4; ++r) {
            const int row = mtile * 16 + quad * 4 + r;
            float p = 0.f;
#pragma unroll
            for (int nt = 0; nt < 4; ++nt) {
                const float v = fmaxf(acc4[nt][r] + biasv[nt], 0.f);
                p += v * woutv[nt];
            }
            p += __shfl_xor(p, 1);
            p += __shfl_xor(p, 2);
            p += __shfl_xor(p, 4);
            p += __shfl_xor(p, 8);
            if (ln == 0) redH[row * 2 + (wv >> 1)] = p;
        }
        __syncthreads();
        if (t < 32) {
            const int gr = i0 + t;
            if (gr < N) out[gr] = redH[t * 2] + redH[t * 2 + 1] + b0;
        }
    }
}

extern "C" void kernel_launch(void* const* d_in, const int* in_sizes, int n_in,
                              void* d_out, int out_size, void* d_ws,
                              size_t ws_size, hipStream_t stream) {
    const float* x = (const float*)d_in[0];
    const int* ei = (const int*)d_in[1];
    const float* W1l = (const float*)d_in[2];
    const float* b1l = (const float*)d_in[3];
    const float* W1r = (const float*)d_in[4];
    const float* W2l = (const float*)d_in[5];
    const float* b2l = (const float*)d_in[6];
    const float* W2r = (const float*)d_in[7];
    const float* Wout = (const float*)d_in[8];
    const float* bout = (const float*)d_in[9];

    const int N = in_sizes[0] / D;
    const int E = in_sizes[1] / 2;
    const int* src = ei;
    const int* dst = ei + E;

    const int nbins = (N + 31) / 32;  // 32-row tiles (= sage blocks), <= 2048
    const size_t Npad = (size_t)((N + 255) & ~255);
    const size_t Epad = (size_t)((E + 255) & ~255);

    int* deg = (int*)d_ws;                       // [Npad]
    int* cursor = deg + Npad;                    // [Npad]
    int* tile_base = cursor + Npad;              // [2052]
    int* bsum = tile_base + 2052;                // [64]
    float* invL_g = (float*)(bsum + 64);         // [Npad]
    unsigned* csr = (unsigned*)(invL_g + Npad);  // [Epad]
    unsigned short* xb = (unsigned short*)(csr + Epad);
    unsigned short* hb = xb + (size_t)N * D;
    unsigned short* Bt1 = hb + (size_t)N * D;
    unsigned short* Bt2 = Bt1 + 128 * 256;
    float* out = (float*)d_out;

    const int NX4 = N * D / 4;
    const int prep_blocks = (NX4 + 2 * 32768 + 255) / 256;
    const int nsb = (N + SCAN_NPB - 1) / SCAN_NPB;

    hipMemsetAsync(deg, 0, Npad * sizeof(int), stream);
    prep_hist_kernel<<<HB + prep_blocks, 256, 0, stream>>>(
        x, W1l, W1r, W2l, W2r, (uint2*)xb, Bt1, Bt2, NX4, dst, E, deg);
    scan1_kernel<<<nsb, 256, 0, stream>>>(deg, N, bsum);
    scan2_kernel<<<nsb, 256, 0, stream>>>(deg, N, E, nbins, bsum, cursor,
                                          tile_base, invL_g);
    fill_kernel<<<(E + 255) / 256, 256, 0, stream>>>(src, dst, E, cursor, csr);

    sage_kernel<false><<<nbins, 256, 0, stream>>>(
        xb, csr, tile_base, invL_g, Bt1, b1l, nullptr, nullptr, hb, nullptr, N);
    sage_kernel<true><<<nbins, 256, 0, stream>>>(
        hb, csr, tile_base, invL_g, Bt2, b2l, Wout, bout, nullptr, out, N);
}